// Round 10
// baseline (356.585 us; speedup 1.0000x reference)
//
#include <hip/hip_runtime.h>

#define IN_F 256
#define OUT_F 64
#define BKT_BITS 8           // 256 nodes per bucket
#define BKT_NODES 256
#define BKT_CAP 6656         // mean padded 4992, sigma ~64 -> huge margin
#define SRC_BITS 18          // N < 262144
#define SRC_MASK 0x3FFFF
#define BIN_BLOCKS 256       // 1 block/CU, 1024 threads = 16 waves/CU

typedef __attribute__((ext_vector_type(8))) short short8;    // 8 bf16 (4 VGPRs) — MFMA A/B frag
typedef __attribute__((ext_vector_type(4))) float floatx4;   // MFMA C/D frag
typedef __attribute__((ext_vector_type(2))) float floatx2;   // final-hop paired store

static __device__ __forceinline__ short f2bf_rne(float f) {
    unsigned u = __float_as_uint(f);
    unsigned r = (u + 0x7fffu + ((u >> 16) & 1u)) >> 16;  // round-nearest-even
    return (short)r;
}
static __device__ __forceinline__ float bf2f(short s) {
    return __uint_as_float(((unsigned)(unsigned short)s) << 16);
}

// ---------------- CSR build, pass 1: bin into fixed-capacity dst-buckets ----------------
// 256 blocks x 1024 threads: 16 waves/CU, ~16-edge runs per (block,bucket) region,
// 100k reservation atomics. Bucket window written by ONE block -> merges in that XCD's
// L2 (R1 lesson: direct global scatter loses 8x).
__global__ __launch_bounds__(1024) void bin_kernel(const int* __restrict__ src,
                                                   const int* __restrict__ dst,
                                                   const float* __restrict__ w,
                                                   int* __restrict__ bkt_cnt,
                                                   int2* __restrict__ binned, int E, int nbkt) {
    __shared__ int h[512];           // nbkt = 391 <= 512
    int t = threadIdx.x;
    if (t < 512) h[t] = 0;
    __syncthreads();
    int ce = (E + BIN_BLOCKS - 1) / BIN_BLOCKS;           // ~6250 edges per block
    int beg = blockIdx.x * ce;
    int end = min(E, beg + ce);
    for (int e = beg + t; e < end; e += 1024)
        atomicAdd(&h[__builtin_nontemporal_load(dst + e) >> BKT_BITS], 1);
    __syncthreads();
    int c = (t < 512) ? h[t] : 0;
    int r = 0;
    if (t < nbkt && c) r = atomicAdd(&bkt_cnt[t], c);
    __syncthreads();
    if (t < 512) h[t] = r;   // becomes block-local cursor (offset within bucket region)
    __syncthreads();
    for (int e = beg + t; e < end; e += 1024) {
        int d = dst[e];
        int bb = d >> BKT_BITS;
        int pos = atomicAdd(&h[bb], 1);
        binned[(size_t)bb * BKT_CAP + pos] =
            make_int2(((d & (BKT_NODES - 1)) << SRC_BITS) | src[e], __float_as_int(w[e]));
    }
}

// ---------------- prep: W -> bf16 hi/lo MFMA B-fragments (blocks 0-7) + zero (blocks 8-9) --
__global__ void prep_kernel(const float* __restrict__ W,
                            short* __restrict__ bh, short* __restrict__ bl,
                            int* __restrict__ bkt_cnt, int nbkt) {
    int blk = blockIdx.x;
    if (blk >= 8) {
        int i = (blk - 8) * 256 + threadIdx.x;
        if (i < nbkt) bkt_cnt[i] = 0;
        return;
    }
    int t = blk * 256 + threadIdx.x;
    int combo = t >> 6;
    int lane = t & 63;
    int s = combo >> 2;
    int tO = combo & 3;
    int n = 16 * tO + (lane & 15);
    int k0 = 32 * s + (lane >> 4) * 8;
    const float* src = W + (size_t)n * IN_F + k0;
    short* dh = bh + (size_t)t * 8;
    short* dl = bl + (size_t)t * 8;
#pragma unroll
    for (int j = 0; j < 8; ++j) {
        float v = src[j];
        short h = f2bf_rne(v);
        dh[j] = h;
        dl[j] = f2bf_rne(v - bf2f(h));
    }
}

// ---------------- FUSED: CSR build pass 2 (blocks 0..nbkt-1) + GEMM (remaining blocks) ----
// Independent work units overlapped in one dispatch: build is atomic/LDS-latency-bound,
// gemm is HBM-BW-bound -> they co-schedule instead of serializing (saves ~1 boundary +
// ~min(t_build, t_gemm)). binned is de-aliased from bufA to make this legal.
__global__ __launch_bounds__(256) void build_gemm_kernel(
        const int2* __restrict__ binned, const int* __restrict__ bkt_cnt,
        int2* __restrict__ bego, int2* __restrict__ edges, int nbkt,
        const float* __restrict__ x, const short8* __restrict__ bh,
        const short8* __restrict__ bl, const float* __restrict__ bias,
        unsigned short* __restrict__ obf, int N) {
    __shared__ int h[BKT_NODES];
    __shared__ int ssum[256];
    int t = threadIdx.x;
    if ((int)blockIdx.x < nbkt) {
        // ---- build_bucket: per-bucket count + padded scan + place + pad ----
        int bkt = blockIdx.x;
        h[t] = 0;
        __syncthreads();
        int cntb = bkt_cnt[bkt];
        const int2* bsrc = binned + (size_t)bkt * BKT_CAP;
        for (int e = t; e < cntb; e += 256) atomicAdd(&h[bsrc[e].x >> SRC_BITS], 1);
        __syncthreads();
        int c = h[t];
        int p = (c + 7) & ~7;          // padded slot count (pads: src 0, w 0)
        ssum[t] = p;
        __syncthreads();
        for (int off = 1; off < 256; off <<= 1) {
            int v = (t >= off) ? ssum[t - off] : 0;
            __syncthreads();
            ssum[t] += v;
            __syncthreads();
        }
        int base = bkt * BKT_CAP + (t > 0 ? ssum[t - 1] : 0);
        int node = (bkt << BKT_BITS) + t;
        if (node < N) bego[node] = make_int2(base, base + p);
        __syncthreads();  // all reads of h-as-counts done
        h[t] = base;
        __syncthreads();
        for (int e = t; e < cntb; e += 256) {
            int2 v = bsrc[e];
            int pos = atomicAdd(&h[v.x >> SRC_BITS], 1);
            edges[pos] = make_int2(v.x & SRC_MASK, v.y);
        }
        __syncthreads();  // cursors final: base + exact count
        for (int k = h[t]; k < base + p; ++k) edges[k] = make_int2(0, 0);
        return;
    }
    // ---- gemm: MFMA bf16x3, output rows stored bf16 (128B/row) ----
    int lane = t & 63;
    int wid = t >> 6;
    int node0 = ((int)blockIdx.x - nbkt) * 64 + wid * 16;
    if (node0 >= N) return;
    if (node0 + 16 > N) node0 = N - 16;
    int m = lane & 15;
    int q = lane >> 4;

    const floatx4* xr = (const floatx4*)(x + (size_t)(node0 + m) * IN_F) + q * 2;

    floatx4 acc[4];
#pragma unroll
    for (int tO = 0; tO < 4; ++tO) acc[tO] = (floatx4){0.f, 0.f, 0.f, 0.f};

#pragma unroll
    for (int s = 0; s < 8; ++s) {
        floatx4 v0 = __builtin_nontemporal_load(xr + s * 8);
        floatx4 v1 = __builtin_nontemporal_load(xr + s * 8 + 1);
        float vv[8] = {v0[0], v0[1], v0[2], v0[3], v1[0], v1[1], v1[2], v1[3]};
        short8 ah, al;
#pragma unroll
        for (int j = 0; j < 8; ++j) {
            short hh = f2bf_rne(vv[j]);
            ah[j] = hh;
            al[j] = f2bf_rne(vv[j] - bf2f(hh));
        }
#pragma unroll
        for (int tO = 0; tO < 4; ++tO) {
            short8 wh = bh[(s * 4 + tO) * 64 + lane];
            short8 wl = bl[(s * 4 + tO) * 64 + lane];
            acc[tO] = __builtin_amdgcn_mfma_f32_16x16x32_bf16(ah, wh, acc[tO], 0, 0, 0);
            acc[tO] = __builtin_amdgcn_mfma_f32_16x16x32_bf16(al, wh, acc[tO], 0, 0, 0);
            acc[tO] = __builtin_amdgcn_mfma_f32_16x16x32_bf16(ah, wl, acc[tO], 0, 0, 0);
        }
    }

#pragma unroll
    for (int tO = 0; tO < 4; ++tO) {
        float bv = bias[16 * tO + m];
#pragma unroll
        for (int r = 0; r < 4; ++r) {
            obf[(size_t)(node0 + q * 4 + r) * OUT_F + 16 * tO + m] =
                (unsigned short)f2bf_rne(acc[tO][r] + bv);
        }
    }
}

// ---------------- SpMM, pair-edge gather ----------------
// Lanes 0-31 process even edges, 32-63 odd edges; each lane gathers a DWORD (2 bf16
// features). Per node: deg/2 gather instrs (vs deg) + deg/2 broadcast 8B edge loads ->
// 1.5x fewer VMEM instrs, 2x edges in flight at same vmcnt depth (latency regime).
// Merge even/odd partials with one shfl_xor(32); lanes 0-31 store packed dwords.
#define GATHER_P(NS)                                                                     \
    {                                                                                    \
        int2 Ev[NS];                                                                     \
        unsigned dv[NS];                                                                 \
        _Pragma("unroll") for (int j = 0; j < NS; ++j) Ev[j] = ed[2 * j + half];         \
        _Pragma("unroll") for (int j = 0; j < NS; ++j)                                   \
            dv[j] = *(const unsigned*)(in + (size_t)Ev[j].x * OUT_F + fl2);              \
        _Pragma("unroll") for (int j = 0; j < NS; ++j) {                                 \
            float wv = __int_as_float(Ev[j].y);                                          \
            a0 = fmaf(wv, __uint_as_float(dv[j] << 16), a0);                             \
            a1 = fmaf(wv, __uint_as_float(dv[j] & 0xFFFF0000u), a1);                     \
        }                                                                                \
    }

// OUT_BF=true: hop1/2, store packed bf16. OUT_BF=false: final hop, store f32 pairs.
template <bool OUT_BF>
__global__ __launch_bounds__(256) void spmm_kernel(const int2* __restrict__ bego,
                                                   const int2* __restrict__ edges,
                                                   const unsigned short* __restrict__ in,
                                                   void* __restrict__ outp, int N) {
    int gid = blockIdx.x * blockDim.x + threadIdx.x;
    int node = __builtin_amdgcn_readfirstlane(gid >> 6);
    int lane = threadIdx.x & 63;
    if (node >= N) return;
    int half = lane >> 5;            // 0: even edges, 1: odd edges
    int fl2 = (lane & 31) * 2;       // feature pair (2*fl, 2*fl+1)
    int2 be = bego[node];            // wave-uniform -> one s_load_dwordx2
    int deg = be.y - be.x;
    const int2* ed = edges + be.x;   // 64B-aligned (beg multiple of 8)
    float a0 = 0.f, a1 = 0.f;
    if (deg == 16) {
        GATHER_P(8)
    } else if (deg == 24) {
        GATHER_P(12)
    } else if (deg == 8) {
        GATHER_P(4)
    } else {
        while (deg >= 32) {
            GATHER_P(16)
            ed += 32;
            deg -= 32;
        }
        if (deg == 24) {
            GATHER_P(12)
        } else if (deg == 16) {
            GATHER_P(8)
        } else if (deg == 8) {
            GATHER_P(4)
        }
    }
    a0 += __shfl_xor(a0, 32);
    a1 += __shfl_xor(a1, 32);
    if (half == 0) {
        int fl = lane & 31;
        if (OUT_BF) {
            unsigned pk = ((unsigned)(unsigned short)f2bf_rne(a1) << 16) |
                          (unsigned)(unsigned short)f2bf_rne(a0);
            __builtin_nontemporal_store(pk, (unsigned*)outp + (size_t)node * 32 + fl);
        } else {
            floatx2 r = {a0, a1};
            __builtin_nontemporal_store(r, (floatx2*)outp + (size_t)node * 32 + fl);
        }
    }
}

// ---------------- launch ----------------
extern "C" void kernel_launch(void* const* d_in, const int* in_sizes, int n_in,
                              void* d_out, int out_size, void* d_ws, size_t ws_size,
                              hipStream_t stream) {
    const float* x = (const float*)d_in[0];
    const float* W = (const float*)d_in[1];
    const float* b = (const float*)d_in[2];
    const int* esrc = (const int*)d_in[3];
    const int* edst = (const int*)d_in[4];
    const float* ew = (const float*)d_in[5];
    float* out = (float*)d_out;

    int N = in_sizes[0] / IN_F;
    int E = in_sizes[3];
    int nbkt = (N + BKT_NODES - 1) >> BKT_BITS;   // 391 for N=100000 (must be <= 512)

    char* ws = (char*)d_ws;
    size_t off = 0;
    unsigned short* bufA = (unsigned short*)(ws + off);  off += (size_t)N * OUT_F * 2;  // 12.8MB
    unsigned short* bufB = (unsigned short*)(ws + off);  off += (size_t)N * OUT_F * 2;  // 12.8MB
    int2* edges = (int2*)(ws + off);     off += (size_t)nbkt * BKT_CAP * sizeof(int2);  // 20.8MB
    int2* binned = (int2*)(ws + off);    off += (size_t)nbkt * BKT_CAP * sizeof(int2);  // 20.8MB
    int2* bego = (int2*)(ws + off);      off += (size_t)N * sizeof(int2);
    int* bkt_cnt = (int*)(ws + off);     off += 1024 * sizeof(int);
    short* bh = (short*)(ws + off);      off += 32 * 64 * 8 * sizeof(short);
    short* bl = (short*)(ws + off);      off += 32 * 64 * 8 * sizeof(short);
    (void)ws_size; (void)n_in; (void)out_size;

    // prep (W frags + zero bkt_cnt), then bin
    prep_kernel<<<10, 256, 0, stream>>>(W, bh, bl, bkt_cnt, nbkt);
    bin_kernel<<<BIN_BLOCKS, 1024, 0, stream>>>(esrc, edst, ew, bkt_cnt, binned, E, nbkt);

    // fused CSR pass 2 + projection (independent units, co-scheduled)
    int gemm_blocks = (N + 63) / 64;
    build_gemm_kernel<<<nbkt + gemm_blocks, 256, 0, stream>>>(
        binned, bkt_cnt, bego, edges, nbkt, x, (const short8*)bh, (const short8*)bl, b,
        bufA, N);

    // 3 hops: bufA -> bufB -> bufA -> out(f32)
    int spmm_blocks = (N * 64 + 255) / 256;
    spmm_kernel<true><<<spmm_blocks, 256, 0, stream>>>(bego, edges, bufA, bufB, N);
    spmm_kernel<true><<<spmm_blocks, 256, 0, stream>>>(bego, edges, bufB, bufA, N);
    spmm_kernel<false><<<spmm_blocks, 256, 0, stream>>>(bego, edges, bufA, out, N);
}

// Round 11
// 354.528 us; speedup vs baseline: 1.0058x; 1.0058x over previous
//
#include <hip/hip_runtime.h>

#define IN_F 256
#define OUT_F 64
#define BKT_BITS 8           // 256 nodes per bucket
#define BKT_NODES 256
#define BKT_CAP 6656         // mean padded 4992, sigma ~64 -> huge margin
#define SRC_BITS 18          // N < 262144
#define SRC_MASK 0x3FFFF
#define BIN_BLOCKS 256       // 1 block/CU, 1024 threads = 16 waves/CU

typedef __attribute__((ext_vector_type(8))) short short8;    // 8 bf16 (4 VGPRs) — MFMA A/B frag
typedef __attribute__((ext_vector_type(4))) float floatx4;   // MFMA C/D frag
typedef __attribute__((ext_vector_type(2))) float floatx2;   // final-hop paired store

static __device__ __forceinline__ short f2bf_rne(float f) {
    unsigned u = __float_as_uint(f);
    unsigned r = (u + 0x7fffu + ((u >> 16) & 1u)) >> 16;  // round-nearest-even
    return (short)r;
}
static __device__ __forceinline__ float bf2f(short s) {
    return __uint_as_float(((unsigned)(unsigned short)s) << 16);
}

// ---------------- CSR build, pass 1: bin into fixed-capacity dst-buckets ----------------
// 256 blocks x 1024 threads: 16 waves/CU, ~16-edge runs per (block,bucket) region,
// 100k reservation atomics. Bucket window written by ONE block -> merges in that XCD's
// L2 (R1 lesson: direct global scatter loses 8x).
__global__ __launch_bounds__(1024) void bin_kernel(const int* __restrict__ src,
                                                   const int* __restrict__ dst,
                                                   const float* __restrict__ w,
                                                   int* __restrict__ bkt_cnt,
                                                   int2* __restrict__ binned, int E, int nbkt) {
    __shared__ int h[512];           // nbkt = 391 <= 512
    int t = threadIdx.x;
    if (t < 512) h[t] = 0;
    __syncthreads();
    int ce = (E + BIN_BLOCKS - 1) / BIN_BLOCKS;           // ~6250 edges per block
    int beg = blockIdx.x * ce;
    int end = min(E, beg + ce);
    for (int e = beg + t; e < end; e += 1024)
        atomicAdd(&h[__builtin_nontemporal_load(dst + e) >> BKT_BITS], 1);
    __syncthreads();
    int c = (t < 512) ? h[t] : 0;
    int r = 0;
    if (t < nbkt && c) r = atomicAdd(&bkt_cnt[t], c);
    __syncthreads();
    if (t < 512) h[t] = r;   // becomes block-local cursor (offset within bucket region)
    __syncthreads();
    for (int e = beg + t; e < end; e += 1024) {
        int d = dst[e];
        int bb = d >> BKT_BITS;
        int pos = atomicAdd(&h[bb], 1);
        binned[(size_t)bb * BKT_CAP + pos] =
            make_int2(((d & (BKT_NODES - 1)) << SRC_BITS) | src[e], __float_as_int(w[e]));
    }
}

// ---------------- CSR build, pass 2 (fused): per-bucket count + padded scan + place + pad --
// Node slot counts rounded to a multiple of 8 (pads = src 0, w 0) so spmm has no remainder.
// Separate kernel (NOT fused with gemm): R10 showed block-branch fusion serializes the
// dispatch and strangles gemm's VGPR budget (62.8 us fused vs ~45 serial).
__global__ __launch_bounds__(256) void build_bucket_kernel(const int2* __restrict__ binned,
                                                           const int* __restrict__ bkt_cnt,
                                                           int2* __restrict__ bego,
                                                           int2* __restrict__ edges,
                                                           int N) {
    __shared__ int h[BKT_NODES];   // per-node counts, then cursors
    __shared__ int ssum[256];
    int t = threadIdx.x;
    int b = blockIdx.x;
    h[t] = 0;
    __syncthreads();
    int cntb = bkt_cnt[b];
    const int2* bsrc = binned + (size_t)b * BKT_CAP;
    for (int e = t; e < cntb; e += 256) atomicAdd(&h[bsrc[e].x >> SRC_BITS], 1);
    __syncthreads();
    int c = h[t];
    int p = (c + 7) & ~7;          // padded slot count
    ssum[t] = p;
    __syncthreads();
    for (int off = 1; off < 256; off <<= 1) {
        int v = (t >= off) ? ssum[t - off] : 0;
        __syncthreads();
        ssum[t] += v;
        __syncthreads();
    }
    int base = b * BKT_CAP + (t > 0 ? ssum[t - 1] : 0);
    int node = (b << BKT_BITS) + t;
    if (node < N) bego[node] = make_int2(base, base + p);
    __syncthreads();  // all reads of h-as-counts done
    h[t] = base;
    __syncthreads();
    for (int e = t; e < cntb; e += 256) {
        int2 v = bsrc[e];
        int pos = atomicAdd(&h[v.x >> SRC_BITS], 1);
        edges[pos] = make_int2(v.x & SRC_MASK, v.y);
    }
    __syncthreads();  // cursors final: base + exact count
    for (int k = h[t]; k < base + p; ++k) edges[k] = make_int2(0, 0);
}

// ---------------- prep: W -> bf16 hi/lo MFMA B-fragments (blocks 0-7) + zero (blocks 8-9) --
__global__ void prep_kernel(const float* __restrict__ W,
                            short* __restrict__ bh, short* __restrict__ bl,
                            int* __restrict__ bkt_cnt, int nbkt) {
    int blk = blockIdx.x;
    if (blk >= 8) {
        int i = (blk - 8) * 256 + threadIdx.x;
        if (i < nbkt) bkt_cnt[i] = 0;
        return;
    }
    int t = blk * 256 + threadIdx.x;
    int combo = t >> 6;
    int lane = t & 63;
    int s = combo >> 2;
    int tO = combo & 3;
    int n = 16 * tO + (lane & 15);
    int k0 = 32 * s + (lane >> 4) * 8;
    const float* src = W + (size_t)n * IN_F + k0;
    short* dh = bh + (size_t)t * 8;
    short* dl = bl + (size_t)t * 8;
#pragma unroll
    for (int j = 0; j < 8; ++j) {
        float v = src[j];
        short h = f2bf_rne(v);
        dh[j] = h;
        dl[j] = f2bf_rne(v - bf2f(h));
    }
}

// ---------------- GEMM via MFMA bf16x3; output rows stored as bf16 (128B/row) ----------
__global__ __launch_bounds__(256) void gemm_kernel(const float* __restrict__ x,
                                                   const short8* __restrict__ bh,
                                                   const short8* __restrict__ bl,
                                                   const float* __restrict__ b,
                                                   unsigned short* __restrict__ obf, int N) {
    int lane = threadIdx.x & 63;
    int wid = threadIdx.x >> 6;
    int node0 = blockIdx.x * 64 + wid * 16;
    if (node0 >= N) return;
    if (node0 + 16 > N) node0 = N - 16;
    int m = lane & 15;
    int q = lane >> 4;

    // x is a pure 102MB stream with zero reuse: nontemporal keeps L2 for everything else
    const floatx4* xr = (const floatx4*)(x + (size_t)(node0 + m) * IN_F) + q * 2;

    floatx4 acc[4];
#pragma unroll
    for (int tO = 0; tO < 4; ++tO) acc[tO] = (floatx4){0.f, 0.f, 0.f, 0.f};

#pragma unroll
    for (int s = 0; s < 8; ++s) {
        floatx4 v0 = __builtin_nontemporal_load(xr + s * 8);
        floatx4 v1 = __builtin_nontemporal_load(xr + s * 8 + 1);
        float vv[8] = {v0[0], v0[1], v0[2], v0[3], v1[0], v1[1], v1[2], v1[3]};
        short8 ah, al;
#pragma unroll
        for (int j = 0; j < 8; ++j) {
            short h = f2bf_rne(vv[j]);
            ah[j] = h;
            al[j] = f2bf_rne(vv[j] - bf2f(h));
        }
#pragma unroll
        for (int tO = 0; tO < 4; ++tO) {
            short8 wh = bh[(s * 4 + tO) * 64 + lane];
            short8 wl = bl[(s * 4 + tO) * 64 + lane];
            acc[tO] = __builtin_amdgcn_mfma_f32_16x16x32_bf16(ah, wh, acc[tO], 0, 0, 0);
            acc[tO] = __builtin_amdgcn_mfma_f32_16x16x32_bf16(al, wh, acc[tO], 0, 0, 0);
            acc[tO] = __builtin_amdgcn_mfma_f32_16x16x32_bf16(ah, wl, acc[tO], 0, 0, 0);
        }
    }

#pragma unroll
    for (int tO = 0; tO < 4; ++tO) {
        float bias = b[16 * tO + m];
#pragma unroll
        for (int r = 0; r < 4; ++r) {
            obf[(size_t)(node0 + q * 4 + r) * OUT_F + 16 * tO + m] =
                (unsigned short)f2bf_rne(acc[tO][r] + bias);
        }
    }
}

// ---------------- SpMM, pair-edge gather ----------------
// Lanes 0-31 process even edges, 32-63 odd edges; each lane gathers a DWORD (2 bf16
// features). Per node: deg/2 gather instrs (vs deg) + deg/2 broadcast 8B edge loads ->
// 1.5x fewer VMEM instrs, 2x edges in flight at same vmcnt depth (latency regime).
// Merge even/odd partials with one shfl_xor(32); lanes 0-31 store packed dwords.
#define GATHER_P(NS)                                                                     \
    {                                                                                    \
        int2 Ev[NS];                                                                     \
        unsigned dv[NS];                                                                 \
        _Pragma("unroll") for (int j = 0; j < NS; ++j) Ev[j] = ed[2 * j + half];         \
        _Pragma("unroll") for (int j = 0; j < NS; ++j)                                   \
            dv[j] = *(const unsigned*)(in + (size_t)Ev[j].x * OUT_F + fl2);              \
        _Pragma("unroll") for (int j = 0; j < NS; ++j) {                                 \
            float wv = __int_as_float(Ev[j].y);                                          \
            a0 = fmaf(wv, __uint_as_float(dv[j] << 16), a0);                             \
            a1 = fmaf(wv, __uint_as_float(dv[j] & 0xFFFF0000u), a1);                     \
        }                                                                                \
    }

// OUT_BF=true: hop1/2, store packed bf16. OUT_BF=false: final hop, store f32 pairs.
template <bool OUT_BF>
__global__ __launch_bounds__(256) void spmm_kernel(const int2* __restrict__ bego,
                                                   const int2* __restrict__ edges,
                                                   const unsigned short* __restrict__ in,
                                                   void* __restrict__ outp, int N) {
    int gid = blockIdx.x * blockDim.x + threadIdx.x;
    int node = __builtin_amdgcn_readfirstlane(gid >> 6);
    int lane = threadIdx.x & 63;
    if (node >= N) return;
    int half = lane >> 5;            // 0: even edges, 1: odd edges
    int fl2 = (lane & 31) * 2;       // feature pair (2*fl, 2*fl+1)
    int2 be = bego[node];            // wave-uniform -> one s_load_dwordx2
    int deg = be.y - be.x;
    const int2* ed = edges + be.x;   // 64B-aligned (beg multiple of 8)
    float a0 = 0.f, a1 = 0.f;
    if (deg == 16) {
        GATHER_P(8)
    } else if (deg == 24) {
        GATHER_P(12)
    } else if (deg == 8) {
        GATHER_P(4)
    } else {
        while (deg >= 32) {
            GATHER_P(16)
            ed += 32;
            deg -= 32;
        }
        if (deg == 24) {
            GATHER_P(12)
        } else if (deg == 16) {
            GATHER_P(8)
        } else if (deg == 8) {
            GATHER_P(4)
        }
    }
    a0 += __shfl_xor(a0, 32);
    a1 += __shfl_xor(a1, 32);
    if (half == 0) {
        int fl = lane & 31;
        if (OUT_BF) {
            unsigned pk = ((unsigned)(unsigned short)f2bf_rne(a1) << 16) |
                          (unsigned)(unsigned short)f2bf_rne(a0);
            __builtin_nontemporal_store(pk, (unsigned*)outp + (size_t)node * 32 + fl);
        } else {
            floatx2 r = {a0, a1};
            __builtin_nontemporal_store(r, (floatx2*)outp + (size_t)node * 32 + fl);
        }
    }
}

// ---------------- launch ----------------
extern "C" void kernel_launch(void* const* d_in, const int* in_sizes, int n_in,
                              void* d_out, int out_size, void* d_ws, size_t ws_size,
                              hipStream_t stream) {
    const float* x = (const float*)d_in[0];
    const float* W = (const float*)d_in[1];
    const float* b = (const float*)d_in[2];
    const int* esrc = (const int*)d_in[3];
    const int* edst = (const int*)d_in[4];
    const float* ew = (const float*)d_in[5];
    float* out = (float*)d_out;

    int N = in_sizes[0] / IN_F;
    int E = in_sizes[3];
    int nbkt = (N + BKT_NODES - 1) >> BKT_BITS;   // 391 for N=100000 (must be <= 512)

    char* ws = (char*)d_ws;
    size_t off = 0;
    unsigned short* bufA = (unsigned short*)(ws + off);  off += (size_t)N * OUT_F * 2;  // 12.8MB
    unsigned short* bufB = (unsigned short*)(ws + off);  off += (size_t)N * OUT_F * 2;  // 12.8MB
    int2* edges = (int2*)(ws + off);     off += (size_t)nbkt * BKT_CAP * sizeof(int2);  // 20.8MB
    int2* binned = (int2*)(ws + off);    off += (size_t)nbkt * BKT_CAP * sizeof(int2);  // 20.8MB
    int2* bego = (int2*)(ws + off);      off += (size_t)N * sizeof(int2);
    int* bkt_cnt = (int*)(ws + off);     off += 1024 * sizeof(int);
    short* bh = (short*)(ws + off);      off += 32 * 64 * 8 * sizeof(short);
    short* bl = (short*)(ws + off);      off += 32 * 64 * 8 * sizeof(short);
    (void)ws_size; (void)n_in; (void)out_size;

    // prep (W frags + zero bkt_cnt), then CSR build (two separate kernels)
    prep_kernel<<<10, 256, 0, stream>>>(W, bh, bl, bkt_cnt, nbkt);
    bin_kernel<<<BIN_BLOCKS, 1024, 0, stream>>>(esrc, edst, ew, bkt_cnt, binned, E, nbkt);
    build_bucket_kernel<<<nbkt, 256, 0, stream>>>(binned, bkt_cnt, bego, edges, N);

    // projection -> bf16 rows
    gemm_kernel<<<(N + 63) / 64, 256, 0, stream>>>(x, (const short8*)bh, (const short8*)bl,
                                                   b, bufA, N);

    // 3 hops: bufA -> bufB -> bufA -> out(f32)
    int spmm_blocks = (N * 64 + 255) / 256;
    spmm_kernel<true><<<spmm_blocks, 256, 0, stream>>>(bego, edges, bufA, bufB, N);
    spmm_kernel<true><<<spmm_blocks, 256, 0, stream>>>(bego, edges, bufB, bufA, N);
    spmm_kernel<false><<<spmm_blocks, 256, 0, stream>>>(bego, edges, bufA, out, N);
}

// Round 12
// 326.701 us; speedup vs baseline: 1.0915x; 1.0852x over previous
//
#include <hip/hip_runtime.h>

#define IN_F 256
#define OUT_F 64
#define BKT_BITS 8           // 256 nodes per bucket
#define BKT_NODES 256
#define BKT_CAP 6656         // mean padded 4992, sigma ~64 -> huge margin
#define SRC_BITS 18          // N < 262144
#define SRC_MASK 0x3FFFF
#define BIN_BLOCKS 256       // 1 block/CU, 1024 threads = 16 waves/CU

typedef __attribute__((ext_vector_type(8))) short short8;    // 8 bf16 (4 VGPRs) — MFMA A/B frag
typedef __attribute__((ext_vector_type(4))) float floatx4;   // MFMA C/D frag
typedef __attribute__((ext_vector_type(4))) int intx4;       // 2 edges per 16B load

static __device__ __forceinline__ short f2bf_rne(float f) {
    unsigned u = __float_as_uint(f);
    unsigned r = (u + 0x7fffu + ((u >> 16) & 1u)) >> 16;  // round-nearest-even
    return (short)r;
}
static __device__ __forceinline__ float bf2f(short s) {
    return __uint_as_float(((unsigned)(unsigned short)s) << 16);
}
static __device__ __forceinline__ float bfu2f(unsigned short s) {
    return __uint_as_float(((unsigned)s) << 16);
}

// ---------------- bin (blocks 0..255) + W-frag prep (blocks 256,257) ----------------
// Binning: 16 waves/CU, ~16-edge runs per (block,bucket) region, 100k reservation
// atomics. Bucket window written by ONE block -> merges in that XCD's L2 (R1 lesson:
// direct global scatter loses 8x). W-frag blocks are independent work folded in to
// save a dispatch (bkt_cnt zeroing moved to a 4KB hipMemsetAsync).
__global__ __launch_bounds__(1024) void bin_wfrag_kernel(
        const int* __restrict__ src, const int* __restrict__ dst,
        const float* __restrict__ w, int* __restrict__ bkt_cnt,
        int2* __restrict__ binned, int E, int nbkt,
        const float* __restrict__ W, short* __restrict__ bh, short* __restrict__ bl) {
    if ((int)blockIdx.x >= BIN_BLOCKS) {
        // ---- W -> bf16 hi/lo MFMA B-fragments (2048 threads across 2 blocks) ----
        int t = ((int)blockIdx.x - BIN_BLOCKS) * 1024 + threadIdx.x;
        if (t >= 32 * 64) return;
        int combo = t >> 6;
        int lane = t & 63;
        int s = combo >> 2;
        int tO = combo & 3;
        int n = 16 * tO + (lane & 15);
        int k0 = 32 * s + (lane >> 4) * 8;
        const float* srcW = W + (size_t)n * IN_F + k0;
        short* dh = bh + (size_t)t * 8;
        short* dl = bl + (size_t)t * 8;
#pragma unroll
        for (int j = 0; j < 8; ++j) {
            float v = srcW[j];
            short h = f2bf_rne(v);
            dh[j] = h;
            dl[j] = f2bf_rne(v - bf2f(h));
        }
        return;
    }
    __shared__ int h[512];           // nbkt = 391 <= 512
    int t = threadIdx.x;
    if (t < 512) h[t] = 0;
    __syncthreads();
    int ce = (E + BIN_BLOCKS - 1) / BIN_BLOCKS;           // ~6250 edges per block
    int beg = blockIdx.x * ce;
    int end = min(E, beg + ce);
    for (int e = beg + t; e < end; e += 1024)
        atomicAdd(&h[__builtin_nontemporal_load(dst + e) >> BKT_BITS], 1);
    __syncthreads();
    int c = (t < 512) ? h[t] : 0;
    int r = 0;
    if (t < nbkt && c) r = atomicAdd(&bkt_cnt[t], c);
    __syncthreads();
    if (t < 512) h[t] = r;   // becomes block-local cursor (offset within bucket region)
    __syncthreads();
    for (int e = beg + t; e < end; e += 1024) {
        int d = dst[e];
        int bb = d >> BKT_BITS;
        int pos = atomicAdd(&h[bb], 1);
        binned[(size_t)bb * BKT_CAP + pos] =
            make_int2(((d & (BKT_NODES - 1)) << SRC_BITS) | src[e], __float_as_int(w[e]));
    }
}

// ---------------- CSR build, pass 2 (fused): per-bucket count + padded scan + place + pad --
// Node slot counts rounded to a multiple of 8 (pads = src 0, w 0) so spmm has no remainder.
// Separate kernel (NOT fused with gemm): R10 showed block-branch fusion serializes the
// dispatch and strangles gemm's VGPR budget (62.8 us fused vs ~45 serial).
__global__ __launch_bounds__(256) void build_bucket_kernel(const int2* __restrict__ binned,
                                                           const int* __restrict__ bkt_cnt,
                                                           int2* __restrict__ bego,
                                                           int2* __restrict__ edges,
                                                           int N) {
    __shared__ int h[BKT_NODES];   // per-node counts, then cursors
    __shared__ int ssum[256];
    int t = threadIdx.x;
    int b = blockIdx.x;
    h[t] = 0;
    __syncthreads();
    int cntb = bkt_cnt[b];
    const int2* bsrc = binned + (size_t)b * BKT_CAP;
    for (int e = t; e < cntb; e += 256) atomicAdd(&h[bsrc[e].x >> SRC_BITS], 1);
    __syncthreads();
    int c = h[t];
    int p = (c + 7) & ~7;          // padded slot count
    ssum[t] = p;
    __syncthreads();
    for (int off = 1; off < 256; off <<= 1) {
        int v = (t >= off) ? ssum[t - off] : 0;
        __syncthreads();
        ssum[t] += v;
        __syncthreads();
    }
    int base = b * BKT_CAP + (t > 0 ? ssum[t - 1] : 0);
    int node = (b << BKT_BITS) + t;
    if (node < N) bego[node] = make_int2(base, base + p);
    __syncthreads();  // all reads of h-as-counts done
    h[t] = base;
    __syncthreads();
    for (int e = t; e < cntb; e += 256) {
        int2 v = bsrc[e];
        int pos = atomicAdd(&h[v.x >> SRC_BITS], 1);
        edges[pos] = make_int2(v.x & SRC_MASK, v.y);
    }
    __syncthreads();  // cursors final: base + exact count
    for (int k = h[t]; k < base + p; ++k) edges[k] = make_int2(0, 0);
}

// ---------------- GEMM via MFMA bf16x3; output rows stored as bf16 (128B/row) ----------
__global__ __launch_bounds__(256) void gemm_kernel(const float* __restrict__ x,
                                                   const short8* __restrict__ bh,
                                                   const short8* __restrict__ bl,
                                                   const float* __restrict__ b,
                                                   unsigned short* __restrict__ obf, int N) {
    int lane = threadIdx.x & 63;
    int wid = threadIdx.x >> 6;
    int node0 = blockIdx.x * 64 + wid * 16;
    if (node0 >= N) return;
    if (node0 + 16 > N) node0 = N - 16;
    int m = lane & 15;
    int q = lane >> 4;

    // x is a pure 102MB stream with zero reuse: nontemporal keeps L2 for everything else
    const floatx4* xr = (const floatx4*)(x + (size_t)(node0 + m) * IN_F) + q * 2;

    floatx4 acc[4];
#pragma unroll
    for (int tO = 0; tO < 4; ++tO) acc[tO] = (floatx4){0.f, 0.f, 0.f, 0.f};

#pragma unroll
    for (int s = 0; s < 8; ++s) {
        floatx4 v0 = __builtin_nontemporal_load(xr + s * 8);
        floatx4 v1 = __builtin_nontemporal_load(xr + s * 8 + 1);
        float vv[8] = {v0[0], v0[1], v0[2], v0[3], v1[0], v1[1], v1[2], v1[3]};
        short8 ah, al;
#pragma unroll
        for (int j = 0; j < 8; ++j) {
            short h = f2bf_rne(vv[j]);
            ah[j] = h;
            al[j] = f2bf_rne(vv[j] - bf2f(h));
        }
#pragma unroll
        for (int tO = 0; tO < 4; ++tO) {
            short8 wh = bh[(s * 4 + tO) * 64 + lane];
            short8 wl = bl[(s * 4 + tO) * 64 + lane];
            acc[tO] = __builtin_amdgcn_mfma_f32_16x16x32_bf16(ah, wh, acc[tO], 0, 0, 0);
            acc[tO] = __builtin_amdgcn_mfma_f32_16x16x32_bf16(al, wh, acc[tO], 0, 0, 0);
            acc[tO] = __builtin_amdgcn_mfma_f32_16x16x32_bf16(ah, wl, acc[tO], 0, 0, 0);
        }
    }

#pragma unroll
    for (int tO = 0; tO < 4; ++tO) {
        float bias = b[16 * tO + m];
#pragma unroll
        for (int r = 0; r < 4; ++r) {
            obf[(size_t)(node0 + q * 4 + r) * OUT_F + 16 * tO + m] =
                (unsigned short)f2bf_rne(acc[tO][r] + bias);
        }
    }
}

// ---------------- SpMM gather core (R9 proven form): single-edge intx4 gather ----------
// Padded deg distribution: {8: 2%, 16: 53%, 24: 43%, >=32: 1.5%}. Single-shot gather
// paths for 8/16/24; generic 16-loop otherwise. Edge loads PLAIN (not nt): the 12.8MB
// edge stream is re-read by hops 2/3 from the same per-XCD L2 slice -> keep cached.
// (R11 A/B: pair-edge dword-gather variant was -29us — reverted.)
#define GATHER_Q(NB)                                                                     \
    {                                                                                    \
        intx4 Q[NB];                                                                     \
        float v[2 * NB];                                                                 \
        _Pragma("unroll") for (int j = 0; j < NB; ++j) Q[j] = eq[j];                     \
        _Pragma("unroll") for (int j = 0; j < NB; ++j) {                                 \
            v[2 * j]     = bfu2f(in[(size_t)Q[j][0] * OUT_F + lane]);                    \
            v[2 * j + 1] = bfu2f(in[(size_t)Q[j][2] * OUT_F + lane]);                    \
        }                                                                                \
        _Pragma("unroll") for (int j = 0; j < NB; ++j) {                                 \
            acc = fmaf(__int_as_float(Q[j][1]), v[2 * j], acc);                          \
            acc = fmaf(__int_as_float(Q[j][3]), v[2 * j + 1], acc);                      \
        }                                                                                \
    }

static __device__ __forceinline__ float spmm_node(const int2* __restrict__ edges,
                                                  const unsigned short* __restrict__ in,
                                                  int lane, int e, int end) {
    float acc = 0.f;
    int deg = end - e;
    const intx4* eq = (const intx4*)(edges + e);
    if (deg == 16) {
        GATHER_Q(8)
    } else if (deg == 24) {
        GATHER_Q(12)
    } else if (deg == 8) {
        GATHER_Q(4)
    } else {
        while (e + 16 <= end) {
            GATHER_Q(8)
            e += 16;
            eq = (const intx4*)(edges + e);
        }
        if (e < end) {   // exactly 8 remain (padded to multiple of 8)
            GATHER_Q(4)
        }
    }
    return acc;
}

// OUT_BF=true: hop1/2, store bf16 rows. OUT_BF=false: final hop, store f32 to d_out.
template <bool OUT_BF>
__global__ __launch_bounds__(256) void spmm_kernel(const int2* __restrict__ bego,
                                                   const int2* __restrict__ edges,
                                                   const unsigned short* __restrict__ in,
                                                   void* __restrict__ outp, int N) {
    int gid = blockIdx.x * blockDim.x + threadIdx.x;
    int node = __builtin_amdgcn_readfirstlane(gid >> 6);
    int lane = threadIdx.x & 63;
    if (node >= N) return;
    int2 be = bego[node];            // wave-uniform -> one s_load_dwordx2
    float acc = spmm_node(edges, in, lane, be.x, be.y);
    if (OUT_BF) {
        unsigned short r = (unsigned short)f2bf_rne(acc);
        __builtin_nontemporal_store(r, (unsigned short*)outp + (size_t)node * OUT_F + lane);
    } else {
        __builtin_nontemporal_store(acc, (float*)outp + (size_t)node * OUT_F + lane);
    }
}

// ---------------- launch ----------------
extern "C" void kernel_launch(void* const* d_in, const int* in_sizes, int n_in,
                              void* d_out, int out_size, void* d_ws, size_t ws_size,
                              hipStream_t stream) {
    const float* x = (const float*)d_in[0];
    const float* W = (const float*)d_in[1];
    const float* b = (const float*)d_in[2];
    const int* esrc = (const int*)d_in[3];
    const int* edst = (const int*)d_in[4];
    const float* ew = (const float*)d_in[5];
    float* out = (float*)d_out;

    int N = in_sizes[0] / IN_F;
    int E = in_sizes[3];
    int nbkt = (N + BKT_NODES - 1) >> BKT_BITS;   // 391 for N=100000 (must be <= 512)

    char* ws = (char*)d_ws;
    size_t off = 0;
    unsigned short* bufA = (unsigned short*)(ws + off);  off += (size_t)N * OUT_F * 2;  // 12.8MB
    unsigned short* bufB = (unsigned short*)(ws + off);  off += (size_t)N * OUT_F * 2;  // 12.8MB
    int2* edges = (int2*)(ws + off);     off += (size_t)nbkt * BKT_CAP * sizeof(int2);  // 20.8MB
    int2* binned = (int2*)(ws + off);    off += (size_t)nbkt * BKT_CAP * sizeof(int2);  // 20.8MB
    int2* bego = (int2*)(ws + off);      off += (size_t)N * sizeof(int2);
    int* bkt_cnt = (int*)(ws + off);     off += 1024 * sizeof(int);
    short* bh = (short*)(ws + off);      off += 32 * 64 * 8 * sizeof(short);
    short* bl = (short*)(ws + off);      off += 32 * 64 * 8 * sizeof(short);
    (void)ws_size; (void)n_in; (void)out_size;

    // zero reservation counters (4KB, stream-ordered, capturable), then bin + W-frag prep
    hipMemsetAsync(bkt_cnt, 0, 1024 * sizeof(int), stream);
    bin_wfrag_kernel<<<BIN_BLOCKS + 2, 1024, 0, stream>>>(esrc, edst, ew, bkt_cnt, binned,
                                                          E, nbkt, W, bh, bl);
    build_bucket_kernel<<<nbkt, 256, 0, stream>>>(binned, bkt_cnt, bego, edges, N);

    // projection -> bf16 rows
    gemm_kernel<<<(N + 63) / 64, 256, 0, stream>>>(x, (const short8*)bh, (const short8*)bl,
                                                   b, bufA, N);

    // 3 hops: bufA -> bufB -> bufA -> out(f32)
    int spmm_blocks = (N * 64 + 255) / 256;
    spmm_kernel<true><<<spmm_blocks, 256, 0, stream>>>(bego, edges, bufA, bufB, N);
    spmm_kernel<true><<<spmm_blocks, 256, 0, stream>>>(bego, edges, bufB, bufA, N);
    spmm_kernel<false><<<spmm_blocks, 256, 0, stream>>>(bego, edges, bufA, out, N);
}